// Round 5
// baseline (216.435 us; speedup 1.0000x reference)
//
#include <hip/hip_runtime.h>

// MinVarianceWeightsLayer: for each of B SPD 64x64 fp32 matrices S,
// solve S z = 1, output w = z / sum(z) as [B, 64, 1] fp32.
//
// ROUND-13: r10 structure (pure readlane broadcast, ZERO LDS) with the
// REGISTER-PRESSURE TARGET fixed. The session's recurring pathology:
// VGPR_Count 40/52/56/68 across r8-r12, always BELOW the 64 floats of
// r[] alone -- the scheduler's occupancy target (default 8 waves/EU; with
// waves_per_eu(3,4) the max=4 still set a 128-reg target) forces r[] into
// AGPRs and emits v_accvgpr_read/write shuttles inside every dependency
// chain (~1.6x VALU instruction inflation, measured: r10 backed-out 141k
// cyc/SIMD vs 85k ideal), while actual residency is ~3 waves/SIMD anyway.
// Fix: amdgpu_waves_per_eu(3,3) -> pressure target ~170 regs; the natural
// footprint (~110-130) fits entirely in arch VGPRs, no AGPR traffic, and
// the scheduler can keep 8 independent trailing slots in flight.
// Algorithm (validated r9-r12, absmax 2.4e-4): Gauss-Jordan, one wave per
// matrix. Symmetric trailing block => column value u_c(j) == el_c at lane
// j, so broadcasts are v_readlane -> SGPR, consumed as v_fma(nf_vgpr,
// u_sgpr, acc_vgpr). No barriers, no LDS, no cross-wave traffic.

#define NN 64

typedef float v2f __attribute__((ext_vector_type(2)));
typedef float v4f __attribute__((ext_vector_type(4)));

template <int I> struct ic { static constexpr int value = I; };

template <int Start, int End, typename F>
__device__ __forceinline__ void static_for(F&& f) {
    if constexpr (Start < End) {
        f(ic<Start>{});
        static_for<Start + 1, End>(static_cast<F&&>(f));
    }
}

__device__ __forceinline__ float rlane(float v, int lane) {
    return __int_as_float(__builtin_amdgcn_readlane(__float_as_int(v), lane));
}

__device__ __forceinline__ float frcp(float x) {
#if __has_builtin(__builtin_amdgcn_rcpf)
    return __builtin_amdgcn_rcpf(x);   // ~1 ulp; plenty vs 2e-3 abs threshold
#else
    return 1.0f / x;
#endif
}

__global__
__attribute__((amdgpu_flat_work_group_size(256, 256), amdgpu_waves_per_eu(3, 3)))
void minvar_kernel(const float* __restrict__ sigma,
                   float* __restrict__ out,
                   int batch) {
    const int lane = threadIdx.x & 63;
    const int wid  = threadIdx.x >> 6;     // 4 waves/block, 1 matrix each
    const int bid  = blockIdx.x * 4 + wid;
    if (bid >= batch) return;              // no barriers anywhere -> safe

    const float* __restrict__ p = sigma + (size_t)bid * (NN * NN) + (size_t)lane * NN;

    // lane i's row as 32 float2 pairs (all indices compile-time -> VGPRs)
    v2f r[NN / 2];
    static_for<0, NN / 4>([&](auto j4c) {
        constexpr int j4 = decltype(j4c)::value;
        v4f v = reinterpret_cast<const v4f*>(p)[j4];
        r[2 * j4 + 0] = v2f{v.x, v.y};
        r[2 * j4 + 1] = v2f{v.z, v.w};
    });

    float b = 1.0f;                        // RHS: ones
    float d = 1.0f;                        // this lane's pivot (set exactly once)

    static_for<0, 16>([&](auto pc) {
        constexpr int P  = decltype(pc)::value;
        constexpr int k0 = 4 * P;
        constexpr int m0 = 2 * P;          // pair-slots m0, m0+1 are the panel

        // ---- phase 1: in-panel Jordan elimination (readlane only, local) ----
        const float el0  = r[m0].x;                    // A[i][k0] (pre-panel)
        const float piv0 = rlane(el0, k0);
        const float nf0  = (lane != k0) ? (-el0 * frcp(piv0)) : 0.0f;
        d = (lane == k0) ? el0 : d;
        b = fmaf(nf0, rlane(b, k0), b);
        const float u01 = rlane(r[m0].y,     k0);
        const float u02 = rlane(r[m0 + 1].x, k0);
        const float u03 = rlane(r[m0 + 1].y, k0);
        r[m0].y     = fmaf(nf0, u01, r[m0].y);
        r[m0 + 1].x = fmaf(nf0, u02, r[m0 + 1].x);
        r[m0 + 1].y = fmaf(nf0, u03, r[m0 + 1].y);

        const float el1  = r[m0].y;                    // A[i][k0+1] after c0
        const float piv1 = rlane(el1, k0 + 1);
        const float nf1  = (lane != k0 + 1) ? (-el1 * frcp(piv1)) : 0.0f;
        d = (lane == k0 + 1) ? el1 : d;
        b = fmaf(nf1, rlane(b, k0 + 1), b);
        const float u12 = rlane(r[m0 + 1].x, k0 + 1);
        const float u13 = rlane(r[m0 + 1].y, k0 + 1);
        r[m0 + 1].x = fmaf(nf1, u12, r[m0 + 1].x);
        r[m0 + 1].y = fmaf(nf1, u13, r[m0 + 1].y);

        const float el2  = r[m0 + 1].x;                // A[i][k0+2] after c0,c1
        const float piv2 = rlane(el2, k0 + 2);
        const float nf2  = (lane != k0 + 2) ? (-el2 * frcp(piv2)) : 0.0f;
        d = (lane == k0 + 2) ? el2 : d;
        b = fmaf(nf2, rlane(b, k0 + 2), b);
        const float u23 = rlane(r[m0 + 1].y, k0 + 2);
        r[m0 + 1].y = fmaf(nf2, u23, r[m0 + 1].y);

        const float el3  = r[m0 + 1].y;                // A[i][k0+3] after c0..c2
        const float piv3 = rlane(el3, k0 + 3);
        const float nf3  = (lane != k0 + 3) ? (-el3 * frcp(piv3)) : 0.0f;
        d = (lane == k0 + 3) ? el3 : d;
        b = fmaf(nf3, rlane(b, k0 + 3), b);

        if constexpr (P < 15) {
            // ---- phase 3: rank-4 update via readlane broadcast (no LDS) ----
            // u_c(j) == el_c at lane j (symmetric trailing block, post-panel).
            static_for<m0 + 2, NN / 2>([&](auto mc) {
                constexpr int m  = decltype(mc)::value;
                constexpr int j0 = 2 * m;
                constexpr int j1 = 2 * m + 1;
                float ax = r[m].x, ay = r[m].y;
                ax = fmaf(nf0, rlane(el0, j0), ax);
                ay = fmaf(nf0, rlane(el0, j1), ay);
                ax = fmaf(nf1, rlane(el1, j0), ax);
                ay = fmaf(nf1, rlane(el1, j1), ay);
                ax = fmaf(nf2, rlane(el2, j0), ax);
                ay = fmaf(nf2, rlane(el2, j1), ay);
                ax = fmaf(nf3, rlane(el3, j0), ax);
                ay = fmaf(nf3, rlane(el3, j1), ay);
                r[m] = v2f{ax, ay};
            });
        }
    });

    // ---- diagonal system: z = b / d (no back-substitution in Gauss-Jordan) ----
    const float z = b * frcp(d);

    // ---- normalize: w = z / sum(z) ----
    float tot = z;
    #pragma unroll
    for (int off = 32; off >= 1; off >>= 1)
        tot += __shfl_xor(tot, off, 64);

    out[(size_t)bid * NN + lane] = z * frcp(tot);
}

extern "C" void kernel_launch(void* const* d_in, const int* in_sizes, int n_in,
                              void* d_out, int out_size, void* d_ws, size_t ws_size,
                              hipStream_t stream) {
    const float* sigma = (const float*)d_in[0];
    float* out = (float*)d_out;
    const int batch  = in_sizes[0] / (NN * NN);   // 8192
    const int blocks = (batch + 3) / 4;           // 4 matrices per 256-thr block
    minvar_kernel<<<blocks, 256, 0, stream>>>(sigma, out, batch);
}

// Round 6
// 193.892 us; speedup vs baseline: 1.1163x; 1.1163x over previous
//
#include <hip/hip_runtime.h>

// MinVarianceWeightsLayer: for each of B SPD 64x64 fp32 matrices S,
// solve S z = 1, output w = z / sum(z) as [B, 64, 1] fp32.
//
// ROUND-14: calibrated dual-pipe split (x=1/2) + r12 prefetch pipeline +
// waves_per_eu(3,3). Session calibration (r9/r13 counters + static counts):
// v_fma-class VALU ~3.7 cyc effective; ds_read_b128 ~12 cyc/CU. Pipe costs:
// all-LDS = 184k cyc/CU = 77us (r9 measured 87), all-readlane = 138k
// cyc/SIMD = 58us issue + 30us stall (r13 measured 88.6). r11's 5/8 split
// ran as SUM (84us = 48+35, zero overlap: pk_fma right behind its own
// lgkmcnt, only 2-3 resident waves). Fix: groups of 8 trailing slots =
// {issue 4 slots' ds_read_b128} -> {4 readlane slots, ~240 VALU cyc,
// covers ~120cyc DS latency} -> {consume 4 prefetched slots with pk_fma}.
// Balanced at x=1/2: DS 92k cyc/CU (38us) || VALU 95k cyc/SIMD (40us).
// waves_per_eu(3,3): 3-wave budget = 170 regs; prefetch arrays (32 floats,
// compile-time indexed) fit without pressure-squeeze.
// Algorithm (validated r9-r13, absmax 2.44e-4): Gauss-Jordan, one wave
// per matrix, no barriers. Symmetric trailing block => published column
// value u_c(j) == el_c at lane j for both transports.

#define NN 64

typedef float v2f __attribute__((ext_vector_type(2)));
typedef float v4f __attribute__((ext_vector_type(4)));

template <int I> struct ic { static constexpr int value = I; };

template <int Start, int End, typename F>
__device__ __forceinline__ void static_for(F&& f) {
    if constexpr (Start < End) {
        f(ic<Start>{});
        static_for<Start + 1, End>(static_cast<F&&>(f));
    }
}

__device__ __forceinline__ float rlane(float v, int lane) {
    return __int_as_float(__builtin_amdgcn_readlane(__float_as_int(v), lane));
}

__device__ __forceinline__ float frcp(float x) {
#if __has_builtin(__builtin_amdgcn_rcpf)
    return __builtin_amdgcn_rcpf(x);   // ~1 ulp; plenty vs 2e-3 abs threshold
#else
    return 1.0f / x;
#endif
}

__device__ __forceinline__ v2f fma2(v2f a, v2f b, v2f c) {
#if __has_builtin(__builtin_elementwise_fma)
    return __builtin_elementwise_fma(a, b, c);   // -> v_pk_fma_f32
#else
    v2f r; r.x = fmaf(a.x, b.x, c.x); r.y = fmaf(a.y, b.y, c.y); return r;
#endif
}

__global__
__attribute__((amdgpu_flat_work_group_size(256, 256), amdgpu_waves_per_eu(3, 3)))
void minvar_kernel(const float* __restrict__ sigma,
                   float* __restrict__ out,
                   int batch) {
    // [wave][panel parity][ m*8 + c*2 + par ] : u_c[2m+par]
    __shared__ float pb[4][2][2 * NN * 4 / 2];   // 4 waves x 2 x 256 floats = 8 KB

    const int lane = threadIdx.x & 63;
    const int wid  = threadIdx.x >> 6;     // 4 waves/block, 1 matrix each
    const int bid  = blockIdx.x * 4 + wid;
    if (bid >= batch) return;              // no barriers anywhere -> safe

    const float* __restrict__ p = sigma + (size_t)bid * (NN * NN) + (size_t)lane * NN;

    // lane i's row as 32 float2 pairs (all indices compile-time -> VGPRs)
    v2f r[NN / 2];
    static_for<0, NN / 4>([&](auto j4c) {
        constexpr int j4 = decltype(j4c)::value;
        v4f v = reinterpret_cast<const v4f*>(p)[j4];
        r[2 * j4 + 0] = v2f{v.x, v.y};
        r[2 * j4 + 1] = v2f{v.z, v.w};
    });

    float b = 1.0f;                        // RHS: ones
    float d = 1.0f;                        // this lane's pivot (set exactly once)
    const int wbase = (lane >> 1) * 8 + (lane & 1);   // scatter-write index

    static_for<0, 16>([&](auto pc) {
        constexpr int P  = decltype(pc)::value;
        constexpr int k0 = 4 * P;
        constexpr int m0 = 2 * P;          // pair-slots m0, m0+1 are the panel
        float* __restrict__ wb = &pb[wid][P & 1][0];

        // ---- phase 1: in-panel Jordan elimination (readlane only, local) ----
        const float el0  = r[m0].x;                    // A[i][k0] (pre-panel)
        if constexpr (P < 15) wb[wbase + 0] = el0;     // publish early
        const float piv0 = rlane(el0, k0);
        const float nf0  = (lane != k0) ? (-el0 * frcp(piv0)) : 0.0f;
        d = (lane == k0) ? el0 : d;
        b = fmaf(nf0, rlane(b, k0), b);
        const float u01 = rlane(r[m0].y,     k0);
        const float u02 = rlane(r[m0 + 1].x, k0);
        const float u03 = rlane(r[m0 + 1].y, k0);
        r[m0].y     = fmaf(nf0, u01, r[m0].y);
        r[m0 + 1].x = fmaf(nf0, u02, r[m0 + 1].x);
        r[m0 + 1].y = fmaf(nf0, u03, r[m0 + 1].y);

        const float el1  = r[m0].y;                    // A[i][k0+1] after c0
        if constexpr (P < 15) wb[wbase + 2] = el1;
        const float piv1 = rlane(el1, k0 + 1);
        const float nf1  = (lane != k0 + 1) ? (-el1 * frcp(piv1)) : 0.0f;
        d = (lane == k0 + 1) ? el1 : d;
        b = fmaf(nf1, rlane(b, k0 + 1), b);
        const float u12 = rlane(r[m0 + 1].x, k0 + 1);
        const float u13 = rlane(r[m0 + 1].y, k0 + 1);
        r[m0 + 1].x = fmaf(nf1, u12, r[m0 + 1].x);
        r[m0 + 1].y = fmaf(nf1, u13, r[m0 + 1].y);

        const float el2  = r[m0 + 1].x;                // A[i][k0+2] after c0,c1
        if constexpr (P < 15) wb[wbase + 4] = el2;
        const float piv2 = rlane(el2, k0 + 2);
        const float nf2  = (lane != k0 + 2) ? (-el2 * frcp(piv2)) : 0.0f;
        d = (lane == k0 + 2) ? el2 : d;
        b = fmaf(nf2, rlane(b, k0 + 2), b);
        const float u23 = rlane(r[m0 + 1].y, k0 + 2);
        r[m0 + 1].y = fmaf(nf2, u23, r[m0 + 1].y);

        const float el3  = r[m0 + 1].y;                // A[i][k0+3] after c0..c2
        if constexpr (P < 15) wb[wbase + 6] = el3;
        const float piv3 = rlane(el3, k0 + 3);
        const float nf3  = (lane != k0 + 3) ? (-el3 * frcp(piv3)) : 0.0f;
        d = (lane == k0 + 3) ? el3 : d;
        b = fmaf(nf3, rlane(b, k0 + 3), b);

        if constexpr (P < 15) {
            // ---- phase 3: rank-4 update, pipelined dual-pipe, x = 1/2 ----
            // Groups of 8 trailing slots: 4 LDS-prefetch + 4 readlane.
            const v2f n0 = v2f{nf0, nf0}, n1 = v2f{nf1, nf1};
            const v2f n2 = v2f{nf2, nf2}, n3 = v2f{nf3, nf3};
            static_for<0, 4>([&](auto gc) {
                constexpr int G = decltype(gc)::value;
                constexpr int s = m0 + 2 + 8 * G;
                if constexpr (s < NN / 2) {
                    constexpr int e = (s + 8 < NN / 2) ? (s + 8) : (NN / 2);
                    v4f lo[4], hi[4];
                    // pass A: issue DS reads for LDS slots (q = 0..3)
                    static_for<s, e>([&](auto mc) {
                        constexpr int m = decltype(mc)::value;
                        constexpr int q = m - s;
                        if constexpr (q < 4) {
                            lo[q] = *reinterpret_cast<const v4f*>(wb + 8 * m);
                            hi[q] = *reinterpret_cast<const v4f*>(wb + 8 * m + 4);
                        }
                    });
                    // pass B: readlane slots (q = 4..7) — independent of DS,
                    // ~240 VALU cycles covering the DS round-trip latency
                    static_for<s, e>([&](auto mc) {
                        constexpr int m = decltype(mc)::value;
                        constexpr int q = m - s;
                        if constexpr (q >= 4) {
                            constexpr int j0 = 2 * m, j1 = 2 * m + 1;
                            float ax = r[m].x, ay = r[m].y;
                            ax = fmaf(nf0, rlane(el0, j0), ax);
                            ay = fmaf(nf0, rlane(el0, j1), ay);
                            ax = fmaf(nf1, rlane(el1, j0), ax);
                            ay = fmaf(nf1, rlane(el1, j1), ay);
                            ax = fmaf(nf2, rlane(el2, j0), ax);
                            ay = fmaf(nf2, rlane(el2, j1), ay);
                            ax = fmaf(nf3, rlane(el3, j0), ax);
                            ay = fmaf(nf3, rlane(el3, j1), ay);
                            r[m] = v2f{ax, ay};
                        }
                    });
                    // pass C: consume prefetched LDS data
                    static_for<s, e>([&](auto mc) {
                        constexpr int m = decltype(mc)::value;
                        constexpr int q = m - s;
                        if constexpr (q < 4) {
                            v2f acc = r[m];
                            acc = fma2(n0, v2f{lo[q].x, lo[q].y}, acc);
                            acc = fma2(n1, v2f{lo[q].z, lo[q].w}, acc);
                            acc = fma2(n2, v2f{hi[q].x, hi[q].y}, acc);
                            acc = fma2(n3, v2f{hi[q].z, hi[q].w}, acc);
                            r[m] = acc;
                        }
                    });
                }
            });
        }
    });

    // ---- diagonal system: z = b / d (no back-substitution in Gauss-Jordan) ----
    const float z = b * frcp(d);

    // ---- normalize: w = z / sum(z) ----
    float tot = z;
    #pragma unroll
    for (int off = 32; off >= 1; off >>= 1)
        tot += __shfl_xor(tot, off, 64);

    out[(size_t)bid * NN + lane] = z * frcp(tot);
}

extern "C" void kernel_launch(void* const* d_in, const int* in_sizes, int n_in,
                              void* d_out, int out_size, void* d_ws, size_t ws_size,
                              hipStream_t stream) {
    const float* sigma = (const float*)d_in[0];
    float* out = (float*)d_out;
    const int batch  = in_sizes[0] / (NN * NN);   // 8192
    const int blocks = (batch + 3) / 4;           // 4 matrices per 256-thr block
    minvar_kernel<<<blocks, 256, 0, stream>>>(sigma, out, batch);
}

// Round 7
// 192.130 us; speedup vs baseline: 1.1265x; 1.0092x over previous
//
#include <hip/hip_runtime.h>

// MinVarianceWeightsLayer: for each of B SPD 64x64 fp32 matrices S,
// solve S z = 1, output w = z / sum(z) as [B, 64, 1] fp32.
//
// ROUND-15: cross-panel software pipeline. r14 (dual-pipe x=1/2, grouped
// A/B/C prefetch) got the kernel under the 77us harness fills. Remaining
// exposure vs the ~35us issue floor: phase-1's serial rlane->rcp->nf
// chains (16 panels x ~250cyc) run with nothing independent adjacent, and
// issue is IN-ORDER per wave -- textual interleave IS the hiding mechanism.
// Restructure: panel P-1's trailing update is split into group0 (slots
// 2P..2P+5, kept in iteration P-1 so phase-1(P) has its inputs) and REST
// (slots 2P+6..31, DEFERRED into iteration P). Iteration P then runs:
//   col0(P) | REST-G0(P-1) | col1(P) | REST-G1(P-1) | col2(P)
//   | REST-G2(P-1) | col3(P) | group0(P)
// Phase-1(P) touches only slots 2P,2P+1 (disjoint from REST's 2P+6..31)
// and group0(P-1) finalized 2P,2P+1 last iteration -> all deps hold.
// Per-slot accumulation order unchanged (panels in increasing P) ->
// bit-identical to r14. Dual-pipe split x~1/2 kept (balance corrected for
// DS being per-CU vs VALU per-SIMD: 184k*x = 140k*(1-x)+30k -> x=0.52).
// Gauss-Jordan, one wave/matrix, no barriers; readlane u == el_c(lane j)
// by trailing-block symmetry (validated r9-r14, absmax 2.441e-4).

#define NN 64

typedef float v2f __attribute__((ext_vector_type(2)));
typedef float v4f __attribute__((ext_vector_type(4)));

template <int I> struct ic { static constexpr int value = I; };

template <int Start, int End, typename F>
__device__ __forceinline__ void static_for(F&& f) {
    if constexpr (Start < End) {
        f(ic<Start>{});
        static_for<Start + 1, End>(static_cast<F&&>(f));
    }
}

__device__ __forceinline__ float rlane(float v, int lane) {
    return __int_as_float(__builtin_amdgcn_readlane(__float_as_int(v), lane));
}

__device__ __forceinline__ float frcp(float x) {
#if __has_builtin(__builtin_amdgcn_rcpf)
    return __builtin_amdgcn_rcpf(x);   // ~1 ulp; plenty vs 2e-3 abs threshold
#else
    return 1.0f / x;
#endif
}

__device__ __forceinline__ v2f fma2(v2f a, v2f b, v2f c) {
#if __has_builtin(__builtin_elementwise_fma)
    return __builtin_elementwise_fma(a, b, c);   // -> v_pk_fma_f32
#else
    v2f r; r.x = fmaf(a.x, b.x, c.x); r.y = fmaf(a.y, b.y, c.y); return r;
#endif
}

__global__
__attribute__((amdgpu_flat_work_group_size(256, 256), amdgpu_waves_per_eu(3, 3)))
void minvar_kernel(const float* __restrict__ sigma,
                   float* __restrict__ out,
                   int batch) {
    // [wave][panel parity][ m*8 + c*2 + par ] : u_c[2m+par]
    __shared__ float pb[4][2][2 * NN * 4 / 2];   // 4 waves x 2 x 256 floats = 8 KB

    const int lane = threadIdx.x & 63;
    const int wid  = threadIdx.x >> 6;     // 4 waves/block, 1 matrix each
    const int bid  = blockIdx.x * 4 + wid;
    if (bid >= batch) return;              // no barriers anywhere -> safe

    const float* __restrict__ p = sigma + (size_t)bid * (NN * NN) + (size_t)lane * NN;

    // lane i's row as 32 float2 pairs (all indices compile-time -> VGPRs)
    v2f r[NN / 2];
    static_for<0, NN / 4>([&](auto j4c) {
        constexpr int j4 = decltype(j4c)::value;
        v4f v = reinterpret_cast<const v4f*>(p)[j4];
        r[2 * j4 + 0] = v2f{v.x, v.y};
        r[2 * j4 + 1] = v2f{v.z, v.w};
    });

    float b = 1.0f;                        // RHS: ones
    float d = 1.0f;                        // this lane's pivot (set exactly once)
    const int wbase = (lane >> 1) * 8 + (lane & 1);   // scatter-write index

    // carried prev-panel broadcast state (panel P-1's el/nf), set at the
    // end of each iteration's group0
    float el0p = 0.f, el1p = 0.f, el2p = 0.f, el3p = 0.f;
    float nf0p = 0.f, nf1p = 0.f, nf2p = 0.f, nf3p = 0.f;

    static_for<0, 16>([&](auto pc) {
        constexpr int P  = decltype(pc)::value;
        constexpr int k0 = 4 * P;
        constexpr int m0 = 2 * P;          // pair-slots m0, m0+1 are the panel
        float* __restrict__ wb  = &pb[wid][P & 1][0];        // panel P publishes
        float* __restrict__ wbp = &pb[wid][(P & 1) ^ 1][0];  // panel P-1's data

        // ---- deferred trailing update of panel P-1: slots 2P+6..31,
        //      executed as up to 3 groups interleaved between phase-1 cols.
        //      Each group: 4 LDS-prefetch slots + 4 readlane slots (A/B/C).
        auto do_rest_group = [&](auto Gc) {
            constexpr int G = decltype(Gc)::value;
            constexpr int s = 2 * P + 6 + 8 * G;
            if constexpr (P >= 1 && s < NN / 2) {
                constexpr int e = (s + 8 < NN / 2) ? (s + 8) : (NN / 2);
                const v2f n0 = v2f{nf0p, nf0p}, n1 = v2f{nf1p, nf1p};
                const v2f n2 = v2f{nf2p, nf2p}, n3 = v2f{nf3p, nf3p};
                v4f lo[4], hi[4];
                // pass A: issue DS reads (q = 0..3)
                static_for<s, e>([&](auto mc) {
                    constexpr int m = decltype(mc)::value;
                    constexpr int q = m - s;
                    if constexpr (q < 4) {
                        lo[q] = *reinterpret_cast<const v4f*>(wbp + 8 * m);
                        hi[q] = *reinterpret_cast<const v4f*>(wbp + 8 * m + 4);
                    }
                });
                // pass B: readlane slots (q = 4..7), independent of DS
                static_for<s, e>([&](auto mc) {
                    constexpr int m = decltype(mc)::value;
                    constexpr int q = m - s;
                    if constexpr (q >= 4) {
                        constexpr int j0 = 2 * m, j1 = 2 * m + 1;
                        float ax = r[m].x, ay = r[m].y;
                        ax = fmaf(nf0p, rlane(el0p, j0), ax);
                        ay = fmaf(nf0p, rlane(el0p, j1), ay);
                        ax = fmaf(nf1p, rlane(el1p, j0), ax);
                        ay = fmaf(nf1p, rlane(el1p, j1), ay);
                        ax = fmaf(nf2p, rlane(el2p, j0), ax);
                        ay = fmaf(nf2p, rlane(el2p, j1), ay);
                        ax = fmaf(nf3p, rlane(el3p, j0), ax);
                        ay = fmaf(nf3p, rlane(el3p, j1), ay);
                        r[m] = v2f{ax, ay};
                    }
                });
                // pass C: consume prefetched LDS data (q = 0..3)
                static_for<s, e>([&](auto mc) {
                    constexpr int m = decltype(mc)::value;
                    constexpr int q = m - s;
                    if constexpr (q < 4) {
                        v2f acc = r[m];
                        acc = fma2(n0, v2f{lo[q].x, lo[q].y}, acc);
                        acc = fma2(n1, v2f{lo[q].z, lo[q].w}, acc);
                        acc = fma2(n2, v2f{hi[q].x, hi[q].y}, acc);
                        acc = fma2(n3, v2f{hi[q].z, hi[q].w}, acc);
                        r[m] = acc;
                    }
                });
            }
        };

        // ---- phase-1 column 0 (slots m0,m0+1 only; indep of REST) ----
        const float el0  = r[m0].x;                    // A[i][k0] (pre-panel)
        if constexpr (P < 15) wb[wbase + 0] = el0;     // publish early
        const float piv0 = rlane(el0, k0);
        const float nf0  = (lane != k0) ? (-el0 * frcp(piv0)) : 0.0f;
        d = (lane == k0) ? el0 : d;
        b = fmaf(nf0, rlane(b, k0), b);
        const float u01 = rlane(r[m0].y,     k0);
        const float u02 = rlane(r[m0 + 1].x, k0);
        const float u03 = rlane(r[m0 + 1].y, k0);
        r[m0].y     = fmaf(nf0, u01, r[m0].y);
        r[m0 + 1].x = fmaf(nf0, u02, r[m0 + 1].x);
        r[m0 + 1].y = fmaf(nf0, u03, r[m0 + 1].y);

        do_rest_group(ic<0>{});   // panel P-1 trailing, group 0

        // ---- phase-1 column 1 ----
        const float el1  = r[m0].y;                    // A[i][k0+1] after c0
        if constexpr (P < 15) wb[wbase + 2] = el1;
        const float piv1 = rlane(el1, k0 + 1);
        const float nf1  = (lane != k0 + 1) ? (-el1 * frcp(piv1)) : 0.0f;
        d = (lane == k0 + 1) ? el1 : d;
        b = fmaf(nf1, rlane(b, k0 + 1), b);
        const float u12 = rlane(r[m0 + 1].x, k0 + 1);
        const float u13 = rlane(r[m0 + 1].y, k0 + 1);
        r[m0 + 1].x = fmaf(nf1, u12, r[m0 + 1].x);
        r[m0 + 1].y = fmaf(nf1, u13, r[m0 + 1].y);

        do_rest_group(ic<1>{});   // panel P-1 trailing, group 1

        // ---- phase-1 column 2 ----
        const float el2  = r[m0 + 1].x;                // A[i][k0+2] after c0,c1
        if constexpr (P < 15) wb[wbase + 4] = el2;
        const float piv2 = rlane(el2, k0 + 2);
        const float nf2  = (lane != k0 + 2) ? (-el2 * frcp(piv2)) : 0.0f;
        d = (lane == k0 + 2) ? el2 : d;
        b = fmaf(nf2, rlane(b, k0 + 2), b);
        const float u23 = rlane(r[m0 + 1].y, k0 + 2);
        r[m0 + 1].y = fmaf(nf2, u23, r[m0 + 1].y);

        do_rest_group(ic<2>{});   // panel P-1 trailing, group 2

        // ---- phase-1 column 3 ----
        const float el3  = r[m0 + 1].y;                // A[i][k0+3] after c0..c2
        if constexpr (P < 15) wb[wbase + 6] = el3;
        const float piv3 = rlane(el3, k0 + 3);
        const float nf3  = (lane != k0 + 3) ? (-el3 * frcp(piv3)) : 0.0f;
        d = (lane == k0 + 3) ? el3 : d;
        b = fmaf(nf3, rlane(b, k0 + 3), b);

        // ---- group0(P): slots m0+2..m0+7 (3 LDS + 3 readlane), kept in
        //      this iteration so phase-1(P+1) finds slots 2P+2,2P+3 done.
        if constexpr (P < 15) {
            constexpr int s0 = m0 + 2;
            constexpr int e0 = (m0 + 8 < NN / 2) ? (m0 + 8) : (NN / 2);
            const v2f n0 = v2f{nf0, nf0}, n1 = v2f{nf1, nf1};
            const v2f n2 = v2f{nf2, nf2}, n3 = v2f{nf3, nf3};
            v4f lo0[3], hi0[3];
            // pass A: issue DS reads (q = 0..2)
            static_for<s0, e0>([&](auto mc) {
                constexpr int m = decltype(mc)::value;
                constexpr int q = m - s0;
                if constexpr (q < 3) {
                    lo0[q] = *reinterpret_cast<const v4f*>(wb + 8 * m);
                    hi0[q] = *reinterpret_cast<const v4f*>(wb + 8 * m + 4);
                }
            });
            // pass B: readlane slots (q = 3..5)
            static_for<s0, e0>([&](auto mc) {
                constexpr int m = decltype(mc)::value;
                constexpr int q = m - s0;
                if constexpr (q >= 3) {
                    constexpr int j0 = 2 * m, j1 = 2 * m + 1;
                    float ax = r[m].x, ay = r[m].y;
                    ax = fmaf(nf0, rlane(el0, j0), ax);
                    ay = fmaf(nf0, rlane(el0, j1), ay);
                    ax = fmaf(nf1, rlane(el1, j0), ax);
                    ay = fmaf(nf1, rlane(el1, j1), ay);
                    ax = fmaf(nf2, rlane(el2, j0), ax);
                    ay = fmaf(nf2, rlane(el2, j1), ay);
                    ax = fmaf(nf3, rlane(el3, j0), ax);
                    ay = fmaf(nf3, rlane(el3, j1), ay);
                    r[m] = v2f{ax, ay};
                }
            });
            // pass C: consume prefetched LDS data
            static_for<s0, e0>([&](auto mc) {
                constexpr int m = decltype(mc)::value;
                constexpr int q = m - s0;
                if constexpr (q < 3) {
                    v2f acc = r[m];
                    acc = fma2(n0, v2f{lo0[q].x, lo0[q].y}, acc);
                    acc = fma2(n1, v2f{lo0[q].z, lo0[q].w}, acc);
                    acc = fma2(n2, v2f{hi0[q].x, hi0[q].y}, acc);
                    acc = fma2(n3, v2f{hi0[q].z, hi0[q].w}, acc);
                    r[m] = acc;
                }
            });
            // carry panel-P broadcast state into iteration P+1's REST
            el0p = el0; el1p = el1; el2p = el2; el3p = el3;
            nf0p = nf0; nf1p = nf1; nf2p = nf2; nf3p = nf3;
        }
    });

    // ---- diagonal system: z = b / d (no back-substitution in Gauss-Jordan) ----
    const float z = b * frcp(d);

    // ---- normalize: w = z / sum(z) ----
    float tot = z;
    #pragma unroll
    for (int off = 32; off >= 1; off >>= 1)
        tot += __shfl_xor(tot, off, 64);

    out[(size_t)bid * NN + lane] = z * frcp(tot);
}

extern "C" void kernel_launch(void* const* d_in, const int* in_sizes, int n_in,
                              void* d_out, int out_size, void* d_ws, size_t ws_size,
                              hipStream_t stream) {
    const float* sigma = (const float*)d_in[0];
    float* out = (float*)d_out;
    const int batch  = in_sizes[0] / (NN * NN);   // 8192
    const int blocks = (batch + 3) / 4;           // 4 matrices per 256-thr block
    minvar_kernel<<<blocks, 256, 0, stream>>>(sigma, out, batch);
}